// Round 4
// baseline (1083.211 us; speedup 1.0000x reference)
//
#include <hip/hip_runtime.h>

// Hungarian (e-maxx shortest-augmenting-path), 32 independent 128x128 L1
// assignment problems. TWO problems per wave (16 waves total), 2 columns per
// lane per problem, zero LDS, zero barriers, bit-exact fp trajectory per
// problem vs the JAX reference.
//
// R3 lesson: trajectory must be bit-exact (no algorithmic reordering).
// R5/R6 lessons: isolated transforms only; skeleton rewrites of the SAME
// serial chain regress. R8 WIN (561->494): fused v_min_f32_dpp reduction.
// R9 WIN (494->466): ty-input poisoning removes masking cndmask from chain.
// R10 (this round): 2-problem interleave per wave. The single-problem wave is
// ~95% dependency-stalled (134 cy/iter vs ~80 issue slots); a second,
// fully-independent problem's instructions fill those stalls. Requirements:
//   * BRANCHLESS inner loop (branches would split BBs and re-serialize):
//     a finished problem is frozen algebraically, bit-exactly:
//       - eff = done ? 0.0f : delta   (v-=0, w+=0, u_row+=0, minv-=0 are
//         bitwise no-ops; no -0.0 can occur in these accumulators)
//       - u_j0 = done ? -1e13f : u_n  (forces cur ~ +1e13 > minv: way guard
//         never fires, fmin(cur,minv)=minv; enters cur at level 3 -> free)
//       - j0 frozen via scalar cselect; done is sticky
//   * interleaved dual DPP reduction: A/B levels alternate, filling each
//     other's 2-wait-state DPP hazard slots (one asm block, 2 results).
// Lockstep: inner loop runs max(tripA, tripB) per row (~+10-15%), paid for
// by ~1.7x issue-density win.
// (R10 resubmit: previous round hit GPUAcquisitionTimeout — never benched.)

#define NN 128
#define BIGF 1e9f
#define TYBIG 1e13f
#define UFRZ -1e13f

__device__ __forceinline__ int rl_i(int x, int l) {
    return __builtin_amdgcn_readlane(x, l);
}
__device__ __forceinline__ float rl_f(float x, int l) {
    return __uint_as_float((uint32_t)__builtin_amdgcn_readlane((int)__float_as_uint(x), l));
}

// Dual full-wave f32 min -> two uniform SGPR results. A/B DPP levels
// alternate so each v_min_f32_dpp's 2 required wait states are covered by
// the other problem's DPP (2 issue cycles) + s_nop 0.
__device__ __forceinline__ void wave_min2_f(float xA, float xB, float& dA, float& dB) {
    int sA, sB;
    asm("s_nop 1\n\t"
        "v_min_f32_dpp %2, %2, %2 row_shr:1 row_mask:0xf bank_mask:0xf\n\t"
        "v_min_f32_dpp %3, %3, %3 row_shr:1 row_mask:0xf bank_mask:0xf\n\t"
        "s_nop 0\n\t"
        "v_min_f32_dpp %2, %2, %2 row_shr:2 row_mask:0xf bank_mask:0xf\n\t"
        "v_min_f32_dpp %3, %3, %3 row_shr:2 row_mask:0xf bank_mask:0xf\n\t"
        "s_nop 0\n\t"
        "v_min_f32_dpp %2, %2, %2 row_shr:4 row_mask:0xf bank_mask:0xf\n\t"
        "v_min_f32_dpp %3, %3, %3 row_shr:4 row_mask:0xf bank_mask:0xf\n\t"
        "s_nop 0\n\t"
        "v_min_f32_dpp %2, %2, %2 row_shr:8 row_mask:0xf bank_mask:0xf\n\t"
        "v_min_f32_dpp %3, %3, %3 row_shr:8 row_mask:0xf bank_mask:0xf\n\t"
        "s_nop 0\n\t"
        "v_min_f32_dpp %2, %2, %2 row_bcast:15 row_mask:0xa bank_mask:0xf\n\t"
        "v_min_f32_dpp %3, %3, %3 row_bcast:15 row_mask:0xa bank_mask:0xf\n\t"
        "s_nop 0\n\t"
        "v_min_f32_dpp %2, %2, %2 row_bcast:31 row_mask:0xc bank_mask:0xf\n\t"
        "v_min_f32_dpp %3, %3, %3 row_bcast:31 row_mask:0xc bank_mask:0xf\n\t"
        "s_nop 0\n\t"
        "v_readlane_b32 %0, %2, 63\n\t"
        "v_readlane_b32 %1, %3, 63"
        : "=s"(sA), "=s"(sB), "+v"(xA), "+v"(xB));
    dA = __uint_as_float((uint32_t)sA);
    dB = __uint_as_float((uint32_t)sB);
}

__global__ __launch_bounds__(64) void hungarian_kernel(
    const float* __restrict__ preds,
    const float* __restrict__ targets,
    int* __restrict__ out)
{
    const int probA = blockIdx.x * 2;   // this wave solves probA and probA+1
    const int lane = threadIdx.x;

    const float2* pA2 = (const float2*)preds + probA * NN;
    const float2* tA2 = (const float2*)targets + probA * NN;
    const float2* pB2 = pA2 + NN;
    const float2* tB2 = tA2 + NN;

    float2 qavA = pA2[lane], qbvA = pA2[lane + 64];
    float2 tavA = tA2[lane], tbvA = tA2[lane + 64];
    float2 qavB = pB2[lane], qbvB = pB2[lane + 64];
    float2 tavB = tB2[lane], tbvB = tB2[lane + 64];

    const float qrxA0 = qavA.x, qrxA1 = qbvA.x, qryA0 = qavA.y, qryA1 = qbvA.y;
    const float txA0  = tavA.x, txA1  = tbvA.x, tyA0  = tavA.y, tyA1  = tbvA.y;
    const float qrxB0 = qavB.x, qrxB1 = qbvB.x, qryB0 = qavB.y, qryB1 = qbvB.y;
    const float txB0  = tavB.x, txB1  = tbvB.x, tyB0  = tavB.y, tyB1  = tbvB.y;
    const int   col0 = lane + 1, col1 = lane + 65;

    float vA0 = 0.f, vA1 = 0.f, wA0 = 0.f, wA1 = 0.f;
    float qcxA0 = 0.f, qcxA1 = 0.f, qcyA0 = 0.f, qcyA1 = 0.f;
    int   pA0 = 0, pA1 = 0;
    float vB0 = 0.f, vB1 = 0.f, wB0 = 0.f, wB1 = 0.f;
    float qcxB0 = 0.f, qcxB1 = 0.f, qcyB0 = 0.f, qcyB1 = 0.f;
    int   pB0 = 0, pB1 = 0;

    for (int i = 0; i < NN; ++i) {
        // ---- row-start: coords of row i (uniform), both problems ----
        const float qxaA = rl_f(qrxA0, i & 63), qxbA = rl_f(qrxA1, i & 63);
        const float qyaA = rl_f(qryA0, i & 63), qybA = rl_f(qryA1, i & 63);
        const float qixA = (i & 64) ? qxbA : qxaA;
        const float qiyA = (i & 64) ? qybA : qyaA;
        const float qxaB = rl_f(qrxB0, i & 63), qxbB = rl_f(qrxB1, i & 63);
        const float qyaB = rl_f(qryB0, i & 63), qybB = rl_f(qryB1, i & 63);
        const float qixB = (i & 64) ? qxbB : qxaB;
        const float qiyB = (i & 64) ? qybB : qyaB;

        // ---- specialized first step (j0=0, nothing used), both ----
        float minvA0 = (fabsf(qixA - txA0) + fabsf(qiyA - tyA0)) - vA0;
        float minvA1 = (fabsf(qixA - txA1) + fabsf(qiyA - tyA1)) - vA1;
        float minvB0 = (fabsf(qixB - txB0) + fabsf(qiyB - tyB0)) - vB0;
        float minvB1 = (fabsf(qixB - txB1) + fabsf(qiyB - tyB1)) - vB1;
        int   wayA0 = 0, wayA1 = 0, wayB0 = 0, wayB1 = 0;
        bool  usedA0 = false, usedA1 = false, usedB0 = false, usedB1 = false;
        float typA0 = tyA0, typA1 = tyA1, typB0 = tyB0, typB1 = tyB1;

        float dA, dB;
        wave_min2_f(fminf(minvA0, minvA1), fminf(minvB0, minvB1), dA, dB);

        unsigned long long bA0 = __ballot(minvA0 == dA);
        unsigned long long bA1 = __ballot(minvA1 == dA);
        int j1A = bA0 ? (int)__ffsll((long long)bA0) : 64 + (int)__ffsll((long long)bA1);
        unsigned long long bB0 = __ballot(minvB0 == dB);
        unsigned long long bB1 = __ballot(minvB1 == dB);
        int j1B = bB0 ? (int)__ffsll((long long)bB0) : 64 + (int)__ffsll((long long)bB1);

        int  srcA = (j1A - 1) & 63;  bool hiA = j1A > 64;
        int  srcB = (j1B - 1) & 63;  bool hiB = j1B > 64;

        int   i0nA = rl_i(hiA ? pA1 : pA0, srcA);
        float u_nA = rl_f(hiA ? wA1 : wA0, srcA);
        float cqxA = rl_f(hiA ? qcxA1 : qcxA0, srcA);
        float cqyA = rl_f(hiA ? qcyA1 : qcyA0, srcA);
        int   i0nB = rl_i(hiB ? pB1 : pB0, srcB);
        float u_nB = rl_f(hiB ? wB1 : wB0, srcB);
        float cqxB = rl_f(hiB ? qcxB1 : qcxB0, srcB);
        float cqyB = rl_f(hiB ? qcyB1 : qcyB0, srcB);

        minvA0 -= dA; minvA1 -= dA;
        minvB0 -= dB; minvB1 -= dB;
        float u_rowA = dA, u_rowB = dB;
        int   j0A = j1A, j0B = j1B;
        bool  doneA = (i0nA == 0), doneB = (i0nB == 0);
        float u_j0A = doneA ? UFRZ : u_nA;     // freeze-ready from the start
        float u_j0B = doneB ? UFRZ : u_nB;

        if (!(doneA && doneB)) {
            for (int it = 0; it < NN + 2; ++it) {
                // mark used[j0]: poison minv (argmin) + typ (cur). Frozen
                // problem re-marks its free col: idempotent, harmless.
                const bool mkA0 = (col0 == j0A), mkA1 = (col1 == j0A);
                usedA0 |= mkA0; usedA1 |= mkA1;
                minvA0 = mkA0 ? BIGF : minvA0;
                minvA1 = mkA1 ? BIGF : minvA1;
                typA0  = mkA0 ? TYBIG : typA0;
                typA1  = mkA1 ? TYBIG : typA1;
                const bool mkB0 = (col0 == j0B), mkB1 = (col1 == j0B);
                usedB0 |= mkB0; usedB1 |= mkB1;
                minvB0 = mkB0 ? BIGF : minvB0;
                minvB1 = mkB1 ? BIGF : minvB1;
                typB0  = mkB0 ? TYBIG : typB0;
                typB1  = mkB1 ? TYBIG : typB1;

                // used cols: cur == 1e13 exactly; frozen problem: cur ~ 1e13
                // via u_j0 = -1e13 (way guard can never fire, fmin no-op)
                const float curA0 = ((fabsf(cqxA - txA0) + fabsf(cqyA - typA0)) - u_j0A) - vA0;
                const float curA1 = ((fabsf(cqxA - txA1) + fabsf(cqyA - typA1)) - u_j0A) - vA1;
                const float curB0 = ((fabsf(cqxB - txB0) + fabsf(cqyB - typB0)) - u_j0B) - vB0;
                const float curB1 = ((fabsf(cqxB - txB1) + fabsf(cqyB - typB1)) - u_j0B) - vB1;

                if (curA0 < minvA0) wayA0 = j0A;
                if (curA1 < minvA1) wayA1 = j0A;
                if (curB0 < minvB0) wayB0 = j0B;
                if (curB1 < minvB1) wayB1 = j0B;

                minvA0 = fminf(curA0, minvA0);
                minvA1 = fminf(curA1, minvA1);
                minvB0 = fminf(curB0, minvB0);
                minvB1 = fminf(curB1, minvB1);

                wave_min2_f(fminf(minvA0, minvA1), fminf(minvB0, minvB1), dA, dB);

                const float effA = doneA ? 0.0f : dA;   // bit-exact freeze
                const float effB = doneB ? 0.0f : dB;

                bA0 = __ballot(minvA0 == dA);
                bA1 = __ballot(minvA1 == dA);
                j1A = bA0 ? (int)__ffsll((long long)bA0) : 64 + (int)__ffsll((long long)bA1);
                bB0 = __ballot(minvB0 == dB);
                bB1 = __ballot(minvB1 == dB);
                j1B = bB0 ? (int)__ffsll((long long)bB0) : 64 + (int)__ffsll((long long)bB1);

                srcA = (j1A - 1) & 63; hiA = j1A > 64;
                srcB = (j1B - 1) & 63; hiB = j1B > 64;
                const int   i0nAn = rl_i(hiA ? pA1 : pA0, srcA);
                const float u_nnA = rl_f(hiA ? wA1 : wA0, srcA);
                const float nqxA  = rl_f(hiA ? qcxA1 : qcxA0, srcA);
                const float nqyA  = rl_f(hiA ? qcyA1 : qcyA0, srcA);
                const int   i0nBn = rl_i(hiB ? pB1 : pB0, srcB);
                const float u_nnB = rl_f(hiB ? wB1 : wB0, srcB);
                const float nqxB  = rl_f(hiB ? qcxB1 : qcxB0, srcB);
                const float nqyB  = rl_f(hiB ? qcyB1 : qcyB0, srcB);

                // reference-exact dual updates (frozen: eff=+0 -> bitwise
                // no-ops; v/w/u_row never hold -0)
                const float tdA0 = usedA0 ? effA : 0.f;
                const float tdA1 = usedA1 ? effA : 0.f;
                vA0 -= tdA0; wA0 += tdA0;
                vA1 -= tdA1; wA1 += tdA1;
                minvA0 -= effA; minvA1 -= effA;
                u_rowA += effA;
                const float tdB0 = usedB0 ? effB : 0.f;
                const float tdB1 = usedB1 ? effB : 0.f;
                vB0 -= tdB0; wB0 += tdB0;
                vB1 -= tdB1; wB1 += tdB1;
                minvB0 -= effB; minvB1 -= effB;
                u_rowB += effB;

                j0A = doneA ? j0A : j1A;                 // scalar freeze
                j0B = doneB ? j0B : j1B;
                const bool dAn = doneA | (i0nAn == 0);   // sticky done
                const bool dBn = doneB | (i0nBn == 0);
                u_j0A = dAn ? UFRZ : u_nnA;
                u_j0B = dBn ? UFRZ : u_nnB;
                cqxA = nqxA; cqyA = nqyA;
                cqxB = nqxB; cqyB = nqyB;
                doneA = dAn; doneB = dBn;
                if (doneA && doneB) break;
            }
        }

        // ---- augment A: shuffle (p, w, qc) along way chain from j0A ----
        {
            int jj = j0A;
            for (int it = 0; it <= NN; ++it) {
                const int  wsrc = (jj - 1) & 63;
                const bool whi  = jj > 64;
                const int  wva = rl_i(wayA0, wsrc), wvb = rl_i(wayA1, wsrc);
                const int  jn  = whi ? wvb : wva;

                int pn; float wn, xn, yn;
                if (jn == 0) {
                    pn = i + 1; wn = u_rowA; xn = qixA; yn = qiyA;
                } else {
                    const int  s2 = (jn - 1) & 63;
                    const bool h2 = jn > 64;
                    const int   paa = rl_i(pA0, s2),   pbb = rl_i(pA1, s2);
                    const float waa = rl_f(wA0, s2),   wbb = rl_f(wA1, s2);
                    const float xaa = rl_f(qcxA0, s2), xbb = rl_f(qcxA1, s2);
                    const float yaa = rl_f(qcyA0, s2), ybb = rl_f(qcyA1, s2);
                    pn = h2 ? pbb : paa; wn = h2 ? wbb : waa;
                    xn = h2 ? xbb : xaa; yn = h2 ? ybb : yaa;
                }
                if (col0 == jj) { pA0 = pn; wA0 = wn; qcxA0 = xn; qcyA0 = yn; }
                if (col1 == jj) { pA1 = pn; wA1 = wn; qcxA1 = xn; qcyA1 = yn; }
                jj = jn;
                if (jj == 0) break;
            }
        }
        // ---- augment B ----
        {
            int jj = j0B;
            for (int it = 0; it <= NN; ++it) {
                const int  wsrc = (jj - 1) & 63;
                const bool whi  = jj > 64;
                const int  wva = rl_i(wayB0, wsrc), wvb = rl_i(wayB1, wsrc);
                const int  jn  = whi ? wvb : wva;

                int pn; float wn, xn, yn;
                if (jn == 0) {
                    pn = i + 1; wn = u_rowB; xn = qixB; yn = qiyB;
                } else {
                    const int  s2 = (jn - 1) & 63;
                    const bool h2 = jn > 64;
                    const int   paa = rl_i(pB0, s2),   pbb = rl_i(pB1, s2);
                    const float waa = rl_f(wB0, s2),   wbb = rl_f(wB1, s2);
                    const float xaa = rl_f(qcxB0, s2), xbb = rl_f(qcxB1, s2);
                    const float yaa = rl_f(qcyB0, s2), ybb = rl_f(qcyB1, s2);
                    pn = h2 ? pbb : paa; wn = h2 ? wbb : waa;
                    xn = h2 ? xbb : xaa; yn = h2 ? ybb : yaa;
                }
                if (col0 == jj) { pB0 = pn; wB0 = wn; qcxB0 = xn; qcyB0 = yn; }
                if (col1 == jj) { pB1 = pn; wB1 = wn; qcxB1 = xn; qcyB1 = yn; }
                jj = jn;
                if (jj == 0) break;
            }
        }
    }

    out[probA * NN + pA0 - 1] = col0 - 1;
    out[probA * NN + pA1 - 1] = col1 - 1;
    out[(probA + 1) * NN + pB0 - 1] = col0 - 1;
    out[(probA + 1) * NN + pB1 - 1] = col1 - 1;
}

extern "C" void kernel_launch(void* const* d_in, const int* in_sizes, int n_in,
                              void* d_out, int out_size, void* d_ws, size_t ws_size,
                              hipStream_t stream) {
    const float* preds   = (const float*)d_in[0];   // (4,8,128,2) fp32
    const float* targets = (const float*)d_in[1];   // (4,8,128,2) fp32
    int* out = (int*)d_out;                         // (4,8,128) int32

    hungarian_kernel<<<16, 64, 0, stream>>>(preds, targets, out);
}

// Round 6
// 519.566 us; speedup vs baseline: 2.0848x; 2.0848x over previous
//
#include <hip/hip_runtime.h>

// Hungarian (e-maxx shortest-augmenting-path), 32 independent 128x128 L1
// assignment problems. ONE WAVE per problem, 2 columns per lane, zero LDS,
// zero barriers, bit-exact fp trajectory vs the JAX reference.
//
// R3: trajectory must be bit-exact. R5/R6: isolated transforms only.
// R8 WIN (561->494): fused inline-asm v_min_f32_dpp wave reduction.
// R9 WIN (494->466): ty-input poisoning removes masking cndmask from chain.
// R10 FAILED (466->1031): 2 problems/wave. Post-mortem: the loop is
// ISSUE-BOUND, not latency-bound — static count ~42 VALU x 2cy + 26cy
// reduce + ~16 SALU ~= 130cy ~= measured 134cy/iter. One wave issues <=1
// instr/cycle, so a second problem's stream just doubles time. Dual-wave,
// lane-split, and SIMD-sharing variants are all dead for the same reason;
// chain-shortening (R5) is worthless while issue > chain (~100cy).
// R11: revert to R9 + ISSUE-SLOT trims only:
//   * freemask: i0n (matched row of winner) is only tested ==0. Keep two
//     SGPR 64-bit free-col masks (fm0: cols 1..64, fm1: 65..128), updated
//     once per row at the search terminus (~4 SALU). The per-iter
//     cndmask+readlane fetch of p (4cy VALU) becomes a scalar bit test,
//     and the loop-break resolves SALU-only off the ballot.
//   * ffs trim: hi=(b0==0); src=ffsll(hi?b1:b0)-1; j1=src+(hi?65:1)
//     (removes (j1-1)&63 and j1>64 recomputation).
// No fp ops touched -> trajectory bit-identical to R9.
// (R11 resubmit: previous round hit GPUAcquisitionTimeout — never benched.)

#define NN 128
#define BIGF 1e9f
#define TYBIG 1e13f

__device__ __forceinline__ int rl_i(int x, int l) {
    return __builtin_amdgcn_readlane(x, l);
}
__device__ __forceinline__ float rl_f(float x, int l) {
    return __uint_as_float((uint32_t)__builtin_amdgcn_readlane((int)__float_as_uint(x), l));
}

// full-wave (64-lane) f32 min -> uniform SGPR result.
// Fused v_min_f32_dpp chain; s_nop 1 = the 2 required VALU->DPP wait states.
__device__ __forceinline__ float wave_min_f(float x) {
    int d;
    asm("s_nop 1\n\t"
        "v_min_f32_dpp %1, %1, %1 row_shr:1 row_mask:0xf bank_mask:0xf\n\t"
        "s_nop 1\n\t"
        "v_min_f32_dpp %1, %1, %1 row_shr:2 row_mask:0xf bank_mask:0xf\n\t"
        "s_nop 1\n\t"
        "v_min_f32_dpp %1, %1, %1 row_shr:4 row_mask:0xf bank_mask:0xf\n\t"
        "s_nop 1\n\t"
        "v_min_f32_dpp %1, %1, %1 row_shr:8 row_mask:0xf bank_mask:0xf\n\t"
        "s_nop 1\n\t"
        "v_min_f32_dpp %1, %1, %1 row_bcast:15 row_mask:0xa bank_mask:0xf\n\t"
        "s_nop 1\n\t"
        "v_min_f32_dpp %1, %1, %1 row_bcast:31 row_mask:0xc bank_mask:0xf\n\t"
        "s_nop 1\n\t"
        "v_readlane_b32 %0, %1, 63"
        : "=s"(d), "+v"(x));
    return __uint_as_float((uint32_t)d);
}

__global__ __launch_bounds__(64) void hungarian_kernel(
    const float* __restrict__ preds,
    const float* __restrict__ targets,
    int* __restrict__ out)
{
    const int prob = blockIdx.x;
    const int lane = threadIdx.x;

    const float2* p2 = (const float2*)preds + prob * NN;
    const float2* t2 = (const float2*)targets + prob * NN;

    float2 qav = p2[lane], qbv = p2[lane + 64];
    float2 tav = t2[lane], tbv = t2[lane + 64];
    const float qrx0 = qav.x, qrx1 = qbv.x;
    const float qry0 = qav.y, qry1 = qbv.y;
    const float tx0  = tav.x, tx1  = tbv.x;
    const float ty0  = tav.y, ty1  = tbv.y;
    const int   col0 = lane + 1, col1 = lane + 65;

    float v0 = 0.f, v1 = 0.f;       // column duals (reference: start 0)
    float w0 = 0.f, w1 = 0.f;       // u[p[col]] cache (valid when p != 0)
    float qcx0 = 0.f, qcx1 = 0.f;   // pred x of row p[col]
    float qcy0 = 0.f, qcy1 = 0.f;   // pred y of row p[col]
    int   p0 = 0, p1 = 0;           // matched row (1-indexed), 0 = free

    // free-column masks: bit (c-1) of fm0 for cols 1..64, (c-65) of fm1
    unsigned long long fm0 = ~0ull, fm1 = ~0ull;

    for (int i = 0; i < NN; ++i) {
        // coords of current row i (uniform): stable-source readlanes + cselect
        const float qxa = rl_f(qrx0, i & 63), qxb = rl_f(qrx1, i & 63);
        const float qya = rl_f(qry0, i & 63), qyb = rl_f(qry1, i & 63);
        const float qix = (i & 64) ? qxb : qxa;
        const float qiy = (i & 64) ? qyb : qya;

        // ---- specialized first search step: j0 = 0, nothing used ----
        // cur = (cost - u[i+1]) - v with u[i+1] = +0  ->  cost - v (bit-exact)
        float minv0 = (fabsf(qix - tx0) + fabsf(qiy - ty0)) - v0;
        float minv1 = (fabsf(qix - tx1) + fabsf(qiy - ty1)) - v1;
        int   way0 = 0, way1 = 0;
        bool  used0 = false, used1 = false;
        float typ0 = ty0, typ1 = ty1;   // poisonable targets-y (reset per row)

        float m     = fminf(minv0, minv1);
        float delta = wave_min_f(m);
        unsigned long long b0 = __ballot(minv0 == delta);
        unsigned long long b1 = __ballot(minv1 == delta);
        bool hi  = (b0 == 0);
        int  src = (int)__ffsll((long long)(hi ? b1 : b0)) - 1;
        int  j1  = src + (hi ? 65 : 1);

        {
            // winner free? (scalar bit test replaces p cndmask+readlane)
            bool freeWin = (((hi ? fm1 : fm0) >> src) & 1ull) != 0;
            // stable-source fetch (w/qc last written in previous augment)
            float wa = rl_f(hi ? w1 : w0, src);
            float xa = rl_f(hi ? qcx1 : qcx0, src);
            float ya = rl_f(hi ? qcy1 : qcy0, src);
            float u_n = wa;
            float cqx = xa;
            float cqy = ya;

            // step-0 updates: nothing used -> v,w unchanged; minv -= delta
            minv0 -= delta;
            minv1 -= delta;
            float u_row = delta;          // u[i+1] = 0 + delta (exact)
            int   j0    = j1;
            float u_j0  = u_n;

            if (!freeWin) {
                for (int it = 0; it < NN + 2; ++it) {
                    // mark used[j0]: poison its minv (argmin) and its typ
                    // (makes cur self-poisoning). Off the critical path.
                    const bool mk0 = (col0 == j0), mk1 = (col1 == j0);
                    used0 |= mk0; used1 |= mk1;
                    minv0 = mk0 ? BIGF : minv0;
                    minv1 = mk1 ? BIGF : minv1;
                    typ0  = mk0 ? TYBIG : typ0;
                    typ1  = mk1 ? TYBIG : typ1;

                    // used cols: cur == 1e13 exactly (> any minv); unused:
                    // bit-exact reference reduced cost
                    const float cur0 = ((fabsf(cqx - tx0) + fabsf(cqy - typ0)) - u_j0) - v0;
                    const float cur1 = ((fabsf(cqx - tx1) + fabsf(cqy - typ1)) - u_j0) - v1;

                    // way update (used cols can never fire: 1e13 > minv)
                    if (cur0 < minv0) way0 = j0;
                    if (cur1 < minv1) way1 = j0;

                    // minv = fminf(cur, minv): unused -> ref-exact;
                    // used -> keeps decayed poison (~1e9)
                    minv0 = fminf(cur0, minv0);
                    minv1 = fminf(cur1, minv1);

                    // argmin directly on minv (poisoned used cols never win)
                    m     = fminf(minv0, minv1);
                    delta = wave_min_f(m);
                    b0 = __ballot(minv0 == delta);
                    b1 = __ballot(minv1 == delta);
                    hi  = (b0 == 0);
                    src = (int)__ffsll((long long)(hi ? b1 : b0)) - 1;
                    j1  = src + (hi ? 65 : 1);

                    // terminate if winner is a free column (scalar bit test)
                    const bool term = (((hi ? fm1 : fm0) >> src) & 1ull) != 0;
                    const float u_nn = rl_f(hi ? w1 : w0, src);
                    const float nqx  = rl_f(hi ? qcx1 : qcx0, src);
                    const float nqy  = rl_f(hi ? qcy1 : qcy0, src);

                    // reference-exact dual updates: v -= du, u[p] += du;
                    // minv -= delta unconditional (unused: exact; used: poison)
                    const float td0 = used0 ? delta : 0.f;
                    const float td1 = used1 ? delta : 0.f;
                    v0 -= td0; w0 += td0;
                    v1 -= td1; w1 += td1;
                    minv0 -= delta;
                    minv1 -= delta;
                    u_row += delta;

                    j0 = j1; u_j0 = u_nn; cqx = nqx; cqy = nqy;
                    if (term) break;
                }
            }

            // the terminating col j0 leaves the free set (once per row)
            {
                const unsigned long long mkb = 1ull << ((j0 - 1) & 63);
                if (j0 > 64) fm1 &= ~mkb; else fm0 &= ~mkb;
            }

            // ---- augment: shuffle (p, w, qc) along `way` chain from j0 ----
            int jj = j0;
            for (int it = 0; it <= NN; ++it) {
                const int  wsrc = (jj - 1) & 63;
                const bool whi  = jj > 64;
                const int  wva = rl_i(way0, wsrc), wvb = rl_i(way1, wsrc);
                const int  jn  = whi ? wvb : wva;

                int pn; float wn, xn, yn;
                if (jn == 0) {                      // path root: current row
                    pn = i + 1; wn = u_row; xn = qix; yn = qiy;
                } else {
                    const int  s2 = (jn - 1) & 63;
                    const bool h2 = jn > 64;
                    const int   paa = rl_i(p0, s2),   pbb = rl_i(p1, s2);
                    const float waa = rl_f(w0, s2),   wbb = rl_f(w1, s2);
                    const float xaa = rl_f(qcx0, s2), xbb = rl_f(qcx1, s2);
                    const float yaa = rl_f(qcy0, s2), ybb = rl_f(qcy1, s2);
                    pn = h2 ? pbb : paa; wn = h2 ? wbb : waa;
                    xn = h2 ? xbb : xaa; yn = h2 ? ybb : yaa;
                }
                if (col0 == jj) { p0 = pn; w0 = wn; qcx0 = xn; qcy0 = yn; }
                if (col1 == jj) { p1 = pn; w1 = wn; qcx1 = xn; qcy1 = yn; }
                jj = jn;
                if (jj == 0) break;
            }
        }
    }

    // p_[s] = row matched to column col[s]; out[row] = col (0-indexed)
    out[prob * NN + p0 - 1] = col0 - 1;
    out[prob * NN + p1 - 1] = col1 - 1;
}

extern "C" void kernel_launch(void* const* d_in, const int* in_sizes, int n_in,
                              void* d_out, int out_size, void* d_ws, size_t ws_size,
                              hipStream_t stream) {
    const float* preds   = (const float*)d_in[0];   // (4,8,128,2) fp32
    const float* targets = (const float*)d_in[1];   // (4,8,128,2) fp32
    int* out = (int*)d_out;                         // (4,8,128) int32

    hungarian_kernel<<<32, 64, 0, stream>>>(preds, targets, out);
}

// Round 7
// 449.799 us; speedup vs baseline: 2.4082x; 1.1551x over previous
//
#include <hip/hip_runtime.h>

// Hungarian (e-maxx shortest-augmenting-path), 32 independent 128x128 L1
// assignment problems. ONE WAVE per problem, 2 columns per lane, zero LDS,
// zero barriers, bit-exact fp trajectory vs the JAX reference.
//
// R3: trajectory must be bit-exact. R5/R6: isolated transforms only.
// R8 WIN (561->494): fused inline-asm v_min_f32_dpp wave reduction.
// R9 WIN (494->466): ty-input poisoning removes masking cndmask from chain.
// R10 FAILED (466->1031): 2 problems/wave — the wave is ISSUE-bound (1
// instr/cy, wave64 VALU = 2cy); a second problem's stream just doubles time.
// R11 NEUTRAL (466->468): VALU->SALU conversion buys nothing — SALU already
// co-issues free in the odd cycles; binding resource = VALU-exec cycles +
// DPP-hazard s_nops.
// R12 (this round): fill the reduction's 7x s_nop 1 (14 dead cy/iter) with
// delta-independent body VALU, shrinking the body by ~12cy:
//   * way0/way1 cndmask (cc = ballot(cur<minv) computed pre-reduction; way
//     is only read at augment) + the j0 broadcast mov.
//   * LAG-1 pending updates w0+=td0, w1+=td1, u_row+=delta from the PREVIOUS
//     iteration. Legal: fetch readlanes only touch UNUSED lanes (td==0
//     there, so lagged w is identical); augment reads w/u_row only after an
//     explicit post-loop flush. First-iter pendings are +0.0f adds = bitwise
//     no-ops (w/u_row/v never hold -0). fp add order preserved.
// Reduction block length unchanged (28cy); body loses ~6 VALU. Trajectory
// bit-identical by construction.

#define NN 128
#define BIGF 1e9f
#define TYBIG 1e13f

__device__ __forceinline__ int rl_i(int x, int l) {
    return __builtin_amdgcn_readlane(x, l);
}
__device__ __forceinline__ float rl_f(float x, int l) {
    return __uint_as_float((uint32_t)__builtin_amdgcn_readlane((int)__float_as_uint(x), l));
}

// full-wave (64-lane) f32 min -> uniform SGPR result. Plain version (used
// once per row at the specialized first step, where no fillers exist).
__device__ __forceinline__ float wave_min_f(float x) {
    int d;
    asm("s_nop 1\n\t"
        "v_min_f32_dpp %1, %1, %1 row_shr:1 row_mask:0xf bank_mask:0xf\n\t"
        "s_nop 1\n\t"
        "v_min_f32_dpp %1, %1, %1 row_shr:2 row_mask:0xf bank_mask:0xf\n\t"
        "s_nop 1\n\t"
        "v_min_f32_dpp %1, %1, %1 row_shr:4 row_mask:0xf bank_mask:0xf\n\t"
        "s_nop 1\n\t"
        "v_min_f32_dpp %1, %1, %1 row_shr:8 row_mask:0xf bank_mask:0xf\n\t"
        "s_nop 1\n\t"
        "v_min_f32_dpp %1, %1, %1 row_bcast:15 row_mask:0xa bank_mask:0xf\n\t"
        "s_nop 1\n\t"
        "v_min_f32_dpp %1, %1, %1 row_bcast:31 row_mask:0xc bank_mask:0xf\n\t"
        "s_nop 1\n\t"
        "v_readlane_b32 %0, %1, 63"
        : "=s"(d), "+v"(x));
    return __uint_as_float((uint32_t)d);
}

// Reduction with the 6 hazard slots filled by delta-independent work:
//   slot0 (entry): j0 broadcast mov   (covers m-write -> DPP1 hazard)
//   slot1: w0 += td0p                 (lag-1 pending)
//   slot2: w1 += td1p
//   slot3: u_row += sdeltap
//   slot4: way0 = cc0 ? j0 : way0    (same-iteration way update)
//   slot5: way1 = cc1 ? j0 : way1
// Fillers write regs no DPP reads -> no new DPP hazards. way cndmask reads
// the j0 mov written 8+ cy earlier. Final s_nop 1 covers DPP6 -> readlane.
__device__ __forceinline__ float wave_min_fill(
    float m, int j0,
    unsigned long long cc0, unsigned long long cc1,
    int& way0, int& way1,
    float& w0, float& w1, float& u_row,
    float td0p, float td1p, float sdeltap)
{
    int d, tmp;
    asm("v_mov_b32 %2, %8\n\t"
        "v_min_f32_dpp %1, %1, %1 row_shr:1 row_mask:0xf bank_mask:0xf\n\t"
        "v_add_f32 %5, %11, %5\n\t"
        "v_min_f32_dpp %1, %1, %1 row_shr:2 row_mask:0xf bank_mask:0xf\n\t"
        "v_add_f32 %6, %12, %6\n\t"
        "v_min_f32_dpp %1, %1, %1 row_shr:4 row_mask:0xf bank_mask:0xf\n\t"
        "v_add_f32 %7, %13, %7\n\t"
        "v_min_f32_dpp %1, %1, %1 row_shr:8 row_mask:0xf bank_mask:0xf\n\t"
        "v_cndmask_b32 %3, %3, %2, %9\n\t"
        "v_min_f32_dpp %1, %1, %1 row_bcast:15 row_mask:0xa bank_mask:0xf\n\t"
        "v_cndmask_b32 %4, %4, %2, %10\n\t"
        "v_min_f32_dpp %1, %1, %1 row_bcast:31 row_mask:0xc bank_mask:0xf\n\t"
        "s_nop 1\n\t"
        "v_readlane_b32 %0, %1, 63"
        : "=s"(d), "+v"(m), "=&v"(tmp), "+v"(way0), "+v"(way1),
          "+v"(w0), "+v"(w1), "+v"(u_row)
        : "s"(j0), "s"(cc0), "s"(cc1), "v"(td0p), "v"(td1p), "s"(sdeltap));
    return __uint_as_float((uint32_t)d);
}

__global__ __launch_bounds__(64) void hungarian_kernel(
    const float* __restrict__ preds,
    const float* __restrict__ targets,
    int* __restrict__ out)
{
    const int prob = blockIdx.x;
    const int lane = threadIdx.x;

    const float2* p2 = (const float2*)preds + prob * NN;
    const float2* t2 = (const float2*)targets + prob * NN;

    float2 qav = p2[lane], qbv = p2[lane + 64];
    float2 tav = t2[lane], tbv = t2[lane + 64];
    const float qrx0 = qav.x, qrx1 = qbv.x;
    const float qry0 = qav.y, qry1 = qbv.y;
    const float tx0  = tav.x, tx1  = tbv.x;
    const float ty0  = tav.y, ty1  = tbv.y;
    const int   col0 = lane + 1, col1 = lane + 65;

    float v0 = 0.f, v1 = 0.f;       // column duals (reference: start 0)
    float w0 = 0.f, w1 = 0.f;       // u[p[col]] cache (valid when p != 0)
    float qcx0 = 0.f, qcx1 = 0.f;   // pred x of row p[col]
    float qcy0 = 0.f, qcy1 = 0.f;   // pred y of row p[col]
    int   p0 = 0, p1 = 0;           // matched row (1-indexed), 0 = free

    // free-column masks: bit (c-1) of fm0 for cols 1..64, (c-65) of fm1
    unsigned long long fm0 = ~0ull, fm1 = ~0ull;

    for (int i = 0; i < NN; ++i) {
        // coords of current row i (uniform): stable-source readlanes + cselect
        const float qxa = rl_f(qrx0, i & 63), qxb = rl_f(qrx1, i & 63);
        const float qya = rl_f(qry0, i & 63), qyb = rl_f(qry1, i & 63);
        const float qix = (i & 64) ? qxb : qxa;
        const float qiy = (i & 64) ? qyb : qya;

        // ---- specialized first search step: j0 = 0, nothing used ----
        // cur = (cost - u[i+1]) - v with u[i+1] = +0  ->  cost - v (bit-exact)
        float minv0 = (fabsf(qix - tx0) + fabsf(qiy - ty0)) - v0;
        float minv1 = (fabsf(qix - tx1) + fabsf(qiy - ty1)) - v1;
        int   way0 = 0, way1 = 0;
        bool  used0 = false, used1 = false;
        float typ0 = ty0, typ1 = ty1;   // poisonable targets-y (reset per row)

        float m     = fminf(minv0, minv1);
        float delta = wave_min_f(m);
        unsigned long long b0 = __ballot(minv0 == delta);
        unsigned long long b1 = __ballot(minv1 == delta);
        bool hi  = (b0 == 0);
        int  src = (int)__ffsll((long long)(hi ? b1 : b0)) - 1;
        int  j1  = src + (hi ? 65 : 1);

        {
            // winner free? (scalar bit test)
            bool freeWin = (((hi ? fm1 : fm0) >> src) & 1ull) != 0;
            // stable-source fetch (w/qc last written in previous augment)
            float wa = rl_f(hi ? w1 : w0, src);
            float xa = rl_f(hi ? qcx1 : qcx0, src);
            float ya = rl_f(hi ? qcy1 : qcy0, src);
            float u_n = wa;
            float cqx = xa;
            float cqy = ya;

            // step-0 updates: nothing used -> v,w unchanged; minv -= delta
            minv0 -= delta;
            minv1 -= delta;
            float u_row = delta;          // u[i+1] = 0 + delta (exact)
            int   j0    = j1;
            float u_j0  = u_n;

            if (!freeWin) {
                // lag-1 pendings (first application: +0.0f = bitwise no-op)
                float td0p = 0.f, td1p = 0.f, sdeltap = 0.f;

                for (int it = 0; it < NN + 2; ++it) {
                    // mark used[j0]: poison its minv (argmin) and its typ
                    // (makes cur self-poisoning). Off the critical path.
                    const bool mk0 = (col0 == j0), mk1 = (col1 == j0);
                    used0 |= mk0; used1 |= mk1;
                    minv0 = mk0 ? BIGF : minv0;
                    minv1 = mk1 ? BIGF : minv1;
                    typ0  = mk0 ? TYBIG : typ0;
                    typ1  = mk1 ? TYBIG : typ1;

                    // used cols: cur == 1e13 exactly (> any minv); unused:
                    // bit-exact reference reduced cost
                    const float cur0 = ((fabsf(cqx - tx0) + fabsf(cqy - typ0)) - u_j0) - v0;
                    const float cur1 = ((fabsf(cqx - tx1) + fabsf(cqy - typ1)) - u_j0) - v1;

                    // way-guard masks (used cols can never fire: 1e13 > minv);
                    // the way writes themselves happen inside the reduction.
                    const unsigned long long cc0 = __ballot(cur0 < minv0);
                    const unsigned long long cc1 = __ballot(cur1 < minv1);

                    // minv = fminf(cur, minv): unused -> ref-exact;
                    // used -> keeps decayed poison (~1e9)
                    minv0 = fminf(cur0, minv0);
                    minv1 = fminf(cur1, minv1);

                    // argmin on minv; hazard slots apply way (this iter) and
                    // pending w/u_row (previous iter)
                    m     = fminf(minv0, minv1);
                    delta = wave_min_fill(m, j0, cc0, cc1, way0, way1,
                                          w0, w1, u_row, td0p, td1p, sdeltap);

                    b0 = __ballot(minv0 == delta);
                    b1 = __ballot(minv1 == delta);
                    hi  = (b0 == 0);
                    src = (int)__ffsll((long long)(hi ? b1 : b0)) - 1;
                    j1  = src + (hi ? 65 : 1);

                    // terminate if winner is a free column (scalar bit test)
                    const bool term = (((hi ? fm1 : fm0) >> src) & 1ull) != 0;
                    const float u_nn = rl_f(hi ? w1 : w0, src);
                    const float nqx  = rl_f(hi ? qcx1 : qcx0, src);
                    const float nqy  = rl_f(hi ? qcy1 : qcy0, src);

                    // reference-exact dual updates: v -= du now (feeds next
                    // cur); w += du and u_row += delta become pendings;
                    // minv -= delta now (feeds next argmin input)
                    const float td0 = used0 ? delta : 0.f;
                    const float td1 = used1 ? delta : 0.f;
                    v0 -= td0;
                    v1 -= td1;
                    minv0 -= delta;
                    minv1 -= delta;
                    td0p = td0; td1p = td1; sdeltap = delta;

                    j0 = j1; u_j0 = u_nn; cqx = nqx; cqy = nqy;
                    if (term) break;
                }

                // flush the final iteration's pendings before augment reads
                w0 += td0p;
                w1 += td1p;
                u_row += sdeltap;
            }

            // the terminating col j0 leaves the free set (once per row)
            {
                const unsigned long long mkb = 1ull << ((j0 - 1) & 63);
                if (j0 > 64) fm1 &= ~mkb; else fm0 &= ~mkb;
            }

            // ---- augment: shuffle (p, w, qc) along `way` chain from j0 ----
            int jj = j0;
            for (int it = 0; it <= NN; ++it) {
                const int  wsrc = (jj - 1) & 63;
                const bool whi  = jj > 64;
                const int  wva = rl_i(way0, wsrc), wvb = rl_i(way1, wsrc);
                const int  jn  = whi ? wvb : wva;

                int pn; float wn, xn, yn;
                if (jn == 0) {                      // path root: current row
                    pn = i + 1; wn = u_row; xn = qix; yn = qiy;
                } else {
                    const int  s2 = (jn - 1) & 63;
                    const bool h2 = jn > 64;
                    const int   paa = rl_i(p0, s2),   pbb = rl_i(p1, s2);
                    const float waa = rl_f(w0, s2),   wbb = rl_f(w1, s2);
                    const float xaa = rl_f(qcx0, s2), xbb = rl_f(qcx1, s2);
                    const float yaa = rl_f(qcy0, s2), ybb = rl_f(qcy1, s2);
                    pn = h2 ? pbb : paa; wn = h2 ? wbb : waa;
                    xn = h2 ? xbb : xaa; yn = h2 ? ybb : yaa;
                }
                if (col0 == jj) { p0 = pn; w0 = wn; qcx0 = xn; qcy0 = yn; }
                if (col1 == jj) { p1 = pn; w1 = wn; qcx1 = xn; qcy1 = yn; }
                jj = jn;
                if (jj == 0) break;
            }
        }
    }

    // p_[s] = row matched to column col[s]; out[row] = col (0-indexed)
    out[prob * NN + p0 - 1] = col0 - 1;
    out[prob * NN + p1 - 1] = col1 - 1;
}

extern "C" void kernel_launch(void* const* d_in, const int* in_sizes, int n_in,
                              void* d_out, int out_size, void* d_ws, size_t ws_size,
                              hipStream_t stream) {
    const float* preds   = (const float*)d_in[0];   // (4,8,128,2) fp32
    const float* targets = (const float*)d_in[1];   // (4,8,128,2) fp32
    int* out = (int*)d_out;                         // (4,8,128) int32

    hungarian_kernel<<<32, 64, 0, stream>>>(preds, targets, out);
}